// Round 10
// baseline (113.614 us; speedup 1.0000x reference)
//
#include <hip/hip_runtime.h>
#include <math.h>

#define T_TOK 4096
#define D_DIM 2048
#define E_EXP 8

typedef float f32x4 __attribute__((ext_vector_type(4)));

struct TokRec { int e0, e1; float g0, g1; };

// ---------------- Kernel 0: transpose Wg[d][e] -> WgT[e][d] (R5, validated) --
__global__ __launch_bounds__(256) void transpose_kernel(const float* __restrict__ Wg,
                                                        float* __restrict__ WgT) {
    const int d = blockIdx.x * 256 + threadIdx.x;
    const float4 a = *reinterpret_cast<const float4*>(Wg + (size_t)d * E_EXP);
    const float4 b = *reinterpret_cast<const float4*>(Wg + (size_t)d * E_EXP + 4);
    WgT[0 * D_DIM + d] = a.x;
    WgT[1 * D_DIM + d] = a.y;
    WgT[2 * D_DIM + d] = a.z;
    WgT[3 * D_DIM + d] = a.w;
    WgT[4 * D_DIM + d] = b.x;
    WgT[5 * D_DIM + d] = b.y;
    WgT[6 * D_DIM + d] = b.z;
    WgT[7 * D_DIM + d] = b.w;
}

// ---------------- Kernel 1: gating — 4 tokens per wave ----------------------
// The 8 WgT loads per iteration are shared by 4 tokens (4x less L1 traffic
// than R5's 1-token/wave) and give 12 independent loads/iter of ILP.
// Per-token FMA order + reduction identical to R5 -> bit-identical routing.
__global__ __launch_bounds__(256) void gating_kernel(const float* __restrict__ x,
                                                     const float* __restrict__ WgT,
                                                     TokRec* __restrict__ recs) {
    const int wave = threadIdx.x >> 6;
    const int lane = threadIdx.x & 63;
    const int t0 = (blockIdx.x * 4 + wave) * 4;     // 4 consecutive tokens
    const float* xr0 = x + (size_t)(t0 + 0) * D_DIM;
    const float* xr1 = x + (size_t)(t0 + 1) * D_DIM;
    const float* xr2 = x + (size_t)(t0 + 2) * D_DIM;
    const float* xr3 = x + (size_t)(t0 + 3) * D_DIM;

    double acc[4][E_EXP];
#pragma unroll
    for (int j = 0; j < 4; ++j)
#pragma unroll
        for (int e = 0; e < E_EXP; ++e) acc[j][e] = 0.0;

#pragma unroll
    for (int i = 0; i < D_DIM / 256; ++i) {
        const int d = i * 256 + lane * 4;
        const f32x4 x0 = *reinterpret_cast<const f32x4*>(xr0 + d);
        const f32x4 x1 = *reinterpret_cast<const f32x4*>(xr1 + d);
        const f32x4 x2 = *reinterpret_cast<const f32x4*>(xr2 + d);
        const f32x4 x3 = *reinterpret_cast<const f32x4*>(xr3 + d);
#pragma unroll
        for (int e = 0; e < E_EXP; ++e) {
            const f32x4 w = *reinterpret_cast<const f32x4*>(WgT + (size_t)e * D_DIM + d);
            acc[0][e] += (double)x0.x * (double)w.x + (double)x0.y * (double)w.y
                       + (double)x0.z * (double)w.z + (double)x0.w * (double)w.w;
            acc[1][e] += (double)x1.x * (double)w.x + (double)x1.y * (double)w.y
                       + (double)x1.z * (double)w.z + (double)x1.w * (double)w.w;
            acc[2][e] += (double)x2.x * (double)w.x + (double)x2.y * (double)w.y
                       + (double)x2.z * (double)w.z + (double)x2.w * (double)w.w;
            acc[3][e] += (double)x3.x * (double)w.x + (double)x3.y * (double)w.y
                       + (double)x3.z * (double)w.z + (double)x3.w * (double)w.w;
        }
    }
#pragma unroll
    for (int j = 0; j < 4; ++j) {
#pragma unroll
        for (int e = 0; e < E_EXP; ++e) {
            double v = acc[j][e];
#pragma unroll
            for (int off = 32; off > 0; off >>= 1) v += __shfl_xor(v, off, 64);
            acc[j][e] = v;
        }
    }
    if (lane == 0) {
#pragma unroll
        for (int j = 0; j < 4; ++j) {
            double m = acc[j][0];
#pragma unroll
            for (int e = 1; e < E_EXP; ++e) m = (acc[j][e] > m) ? acc[j][e] : m;
            double Z = 0.0;
#pragma unroll
            for (int e = 0; e < E_EXP; ++e) Z += exp(acc[j][e] - m);
            int e0 = 0;
#pragma unroll
            for (int e = 1; e < E_EXP; ++e) if (acc[j][e] > acc[j][e0]) e0 = e;
            int e1 = (e0 == 0) ? 1 : 0;
#pragma unroll
            for (int e = 0; e < E_EXP; ++e) if (e != e0 && acc[j][e] > acc[j][e1]) e1 = e;
            TokRec r;
            r.e0 = e0; r.e1 = e1;
            r.g0 = (float)(exp(acc[j][e0] - m) / Z);
            r.g1 = (float)(exp(acc[j][e1] - m) / Z);
            recs[t0 + j] = r;
        }
    }
}

// ---------------- Kernel 2: single-block scan (R5, validated) ----------------
__global__ __launch_bounds__(256) void scan_kernel(const TokRec* __restrict__ recs,
                                                   int2* __restrict__ smap,
                                                   int* __restrict__ loads_i,
                                                   float* __restrict__ loads_out) {
    __shared__ uint4 sb[256];
    __shared__ int offlds[256 * 8];
    const int tid = threadIdx.x;

    const int t0 = tid * 16;
    unsigned long long c = 0ULL;
    TokRec rl[16];
    for (int k = 0; k < 16; ++k) {
        rl[k] = recs[t0 + k];
        c += 1ULL << (rl[k].e0 * 8);
        c += 1ULL << (rl[k].e1 * 8);
    }
    uint4 v;
    v.x = (unsigned)((c       ) & 0xFF) | ((unsigned)((c >>  8) & 0xFF) << 16);
    v.y = (unsigned)((c >> 16 ) & 0xFF) | ((unsigned)((c >> 24) & 0xFF) << 16);
    v.z = (unsigned)((c >> 32 ) & 0xFF) | ((unsigned)((c >> 40) & 0xFF) << 16);
    v.w = (unsigned)((c >> 48 ) & 0xFF) | ((unsigned)((c >> 56) & 0xFF) << 16);
    const uint4 own = v;
    sb[tid] = v;
    for (int d = 1; d < 256; d <<= 1) {
        __syncthreads();
        uint4 o = make_uint4(0u, 0u, 0u, 0u);
        if (tid >= d) o = sb[tid - d];
        __syncthreads();
        v.x += o.x; v.y += o.y; v.z += o.z; v.w += o.w;
        sb[tid] = v;
    }
    __syncthreads();
    const uint4 tot = sb[255];

    offlds[tid * 8 + 0] = (int)((v.x - own.x) & 0xFFFF);
    offlds[tid * 8 + 1] = (int)((v.x - own.x) >> 16);
    offlds[tid * 8 + 2] = (int)((v.y - own.y) & 0xFFFF);
    offlds[tid * 8 + 3] = (int)((v.y - own.y) >> 16);
    offlds[tid * 8 + 4] = (int)((v.z - own.z) & 0xFFFF);
    offlds[tid * 8 + 5] = (int)((v.z - own.z) >> 16);
    offlds[tid * 8 + 6] = (int)((v.w - own.w) & 0xFFFF);
    offlds[tid * 8 + 7] = (int)((v.w - own.w) >> 16);

    if (tid < 8) {
        unsigned comp = (tid < 2) ? tot.x : (tid < 4) ? tot.y : (tid < 6) ? tot.z : tot.w;
        unsigned val = (tid & 1) ? (comp >> 16) : (comp & 0xFFFF);
        loads_i[tid] = (int)val;
        loads_out[tid] = (float)val;
    }

    const int obase = tid * 8;
    for (int k = 0; k < 16; ++k) {
        const TokRec r = rl[k];
        const int tok = t0 + k;
        int d0 = offlds[obase + r.e0]++;
        smap[r.e0 * T_TOK + d0] = make_int2(tok, __float_as_int(r.g0));
        int d1 = offlds[obase + r.e1]++;
        smap[r.e1 * T_TOK + d1] = make_int2(tok, __float_as_int(r.g1));
    }
}

// ---------------- Kernel 3: scatter (R5, validated) --------------------------
__global__ __launch_bounds__(256) void scatter_kernel(const float* __restrict__ x,
                                                      const int2* __restrict__ smap,
                                                      const int* __restrict__ loads_i,
                                                      float* __restrict__ out_data,
                                                      float* __restrict__ out_tags) {
    const int tid = threadIdx.x;
    const int row0 = blockIdx.x * 4;
    const int base = tid * 8;
    const int e_first = row0 >> 12;
    const int e_last = (row0 + 3) >> 12;
    const int lf = loads_i[e_first];
    const int ll = (e_last != e_first) ? loads_i[e_last] : lf;
#pragma unroll
    for (int k = 0; k < 4; ++k) {
        const int row = row0 + k;
        const int e = row >> 12;
        const int r = row & (T_TOK - 1);
        const int le = (e == e_first) ? lf : ll;
        float* orow = out_data + (size_t)row * D_DIM;
        if (r >= le) {
            if (tid == 0) out_tags[row] = -1.0f;
            const f32x4 z = {0.f, 0.f, 0.f, 0.f};
            *reinterpret_cast<f32x4*>(orow + base) = z;
            *reinterpret_cast<f32x4*>(orow + base + 4) = z;
        } else {
            const int2 sg = smap[row];
            const int src = sg.x;
            const float g = __int_as_float(sg.y);
            if (tid == 0) out_tags[row] = (float)src;
            const float* xr = x + (size_t)src * D_DIM;
            f32x4 a = *reinterpret_cast<const f32x4*>(xr + base);
            f32x4 b = *reinterpret_cast<const f32x4*>(xr + base + 4);
            a *= g;
            b *= g;
            *reinterpret_cast<f32x4*>(orow + base) = a;
            *reinterpret_cast<f32x4*>(orow + base + 4) = b;
        }
    }
}

extern "C" void kernel_launch(void* const* d_in, const int* in_sizes, int n_in,
                              void* d_out, int out_size, void* d_ws, size_t ws_size,
                              hipStream_t stream) {
    const float* x  = (const float*)d_in[0];
    const float* Wg = (const float*)d_in[1];

    float* out       = (float*)d_out;
    float* out_data  = out;
    float* out_tags  = out + (size_t)E_EXP * T_TOK * D_DIM;
    float* out_loads = out_tags + E_EXP * T_TOK;

    char* ws = (char*)d_ws;
    TokRec* recs    = (TokRec*)ws;                         // 64 KiB
    int2*   smap    = (int2*)(ws + 65536);                 // 256 KiB
    int*    loads_i = (int*)(ws + 65536 + 262144);         // 32 B
    float*  WgT     = (float*)(ws + 65536 + 262144 + 1024);// 64 KiB

    transpose_kernel<<<D_DIM / 256, 256, 0, stream>>>(Wg, WgT);
    gating_kernel<<<T_TOK / 16, 256, 0, stream>>>(x, WgT, recs);
    scan_kernel<<<1, 256, 0, stream>>>(recs, smap, loads_i, out_loads);
    scatter_kernel<<<E_EXP * T_TOK / 4, 256, 0, stream>>>(x, smap, loads_i, out_data, out_tags);
}

// Round 11
// 86.028 us; speedup vs baseline: 1.3207x; 1.3207x over previous
//
#include <hip/hip_runtime.h>
#include <math.h>

#define T_TOK 4096
#define D_DIM 2048
#define E_EXP 8

typedef float f32x4 __attribute__((ext_vector_type(4)));

struct TokRec { int e0, e1; float g0, g1; };

// ---------------- Kernel 0: transpose Wg[d][e] -> WgT[e][d] (R5, validated) --
__global__ __launch_bounds__(256) void transpose_kernel(const float* __restrict__ Wg,
                                                        float* __restrict__ WgT) {
    const int d = blockIdx.x * 256 + threadIdx.x;
    const float4 a = *reinterpret_cast<const float4*>(Wg + (size_t)d * E_EXP);
    const float4 b = *reinterpret_cast<const float4*>(Wg + (size_t)d * E_EXP + 4);
    WgT[0 * D_DIM + d] = a.x;
    WgT[1 * D_DIM + d] = a.y;
    WgT[2 * D_DIM + d] = a.z;
    WgT[3 * D_DIM + d] = a.w;
    WgT[4 * D_DIM + d] = b.x;
    WgT[5 * D_DIM + d] = b.y;
    WgT[6 * D_DIM + d] = b.z;
    WgT[7 * D_DIM + d] = b.w;
}

// ---------------- Kernel 1: gating — 2 tokens x half-D per wave -------------
// Same geometry as R5 (1024 blocks x 256 thr = 16 waves/CU — R10's lesson:
// never shrink the grid). Each wave dots 1024 dims for 2 tokens, so each WgT
// load is shared by 2 tokens and only half of WgT is read per wave:
// 16 KB/token vs R5's 64 KB/token of L1/L2 traffic. Half-sums joined in LDS.
__global__ __launch_bounds__(256) void gating_kernel(const float* __restrict__ x,
                                                     const float* __restrict__ WgT,
                                                     TokRec* __restrict__ recs) {
    __shared__ double hsum[4][2][E_EXP];   // [wave][token-in-pair][expert]
    const int wave = threadIdx.x >> 6;
    const int lane = threadIdx.x & 63;
    const int pair = wave >> 1;            // 0,1 -> which token pair
    const int half = wave & 1;             // 0,1 -> which D half
    const int tA = blockIdx.x * 4 + pair * 2;
    const float* xrA = x + (size_t)tA * D_DIM + half * (D_DIM / 2);
    const float* xrB = xrA + D_DIM;
    const float* wgh = WgT + half * (D_DIM / 2);

    double acc[2][E_EXP];
#pragma unroll
    for (int j = 0; j < 2; ++j)
#pragma unroll
        for (int e = 0; e < E_EXP; ++e) acc[j][e] = 0.0;

#pragma unroll
    for (int i = 0; i < (D_DIM / 2) / 256; ++i) {      // 4 iterations
        const int d = i * 256 + lane * 4;
        const f32x4 xa = *reinterpret_cast<const f32x4*>(xrA + d);
        const f32x4 xb = *reinterpret_cast<const f32x4*>(xrB + d);
#pragma unroll
        for (int e = 0; e < E_EXP; ++e) {
            const f32x4 w = *reinterpret_cast<const f32x4*>(wgh + (size_t)e * D_DIM + d);
            acc[0][e] += (double)xa.x * (double)w.x + (double)xa.y * (double)w.y
                       + (double)xa.z * (double)w.z + (double)xa.w * (double)w.w;
            acc[1][e] += (double)xb.x * (double)w.x + (double)xb.y * (double)w.y
                       + (double)xb.z * (double)w.z + (double)xb.w * (double)w.w;
        }
    }
#pragma unroll
    for (int j = 0; j < 2; ++j)
#pragma unroll
        for (int e = 0; e < E_EXP; ++e) {
            double v = acc[j][e];
#pragma unroll
            for (int off = 32; off > 0; off >>= 1) v += __shfl_xor(v, off, 64);
            acc[j][e] = v;
        }
    if (lane == 0) {
#pragma unroll
        for (int j = 0; j < 2; ++j)
#pragma unroll
            for (int e = 0; e < E_EXP; ++e) hsum[wave][j][e] = acc[j][e];
    }
    __syncthreads();
    if (half == 0 && lane == 0) {
#pragma unroll
        for (int j = 0; j < 2; ++j) {
            double lg[E_EXP];
#pragma unroll
            for (int e = 0; e < E_EXP; ++e) lg[e] = hsum[wave][j][e] + hsum[wave + 1][j][e];
            double m = lg[0];
#pragma unroll
            for (int e = 1; e < E_EXP; ++e) m = (lg[e] > m) ? lg[e] : m;
            double Z = 0.0;
#pragma unroll
            for (int e = 0; e < E_EXP; ++e) Z += exp(lg[e] - m);
            int e0 = 0;
#pragma unroll
            for (int e = 1; e < E_EXP; ++e) if (lg[e] > lg[e0]) e0 = e;
            int e1 = (e0 == 0) ? 1 : 0;
#pragma unroll
            for (int e = 0; e < E_EXP; ++e) if (e != e0 && lg[e] > lg[e1]) e1 = e;
            TokRec r;
            r.e0 = e0; r.e1 = e1;
            r.g0 = (float)(exp(lg[e0] - m) / Z);
            r.g1 = (float)(exp(lg[e1] - m) / Z);
            recs[tA + j] = r;
        }
    }
}

// ---------------- Kernel 2: single-block scan (R5, validated) ----------------
__global__ __launch_bounds__(256) void scan_kernel(const TokRec* __restrict__ recs,
                                                   int2* __restrict__ smap,
                                                   int* __restrict__ loads_i,
                                                   float* __restrict__ loads_out) {
    __shared__ uint4 sb[256];
    __shared__ int offlds[256 * 8];
    const int tid = threadIdx.x;

    const int t0 = tid * 16;
    unsigned long long c = 0ULL;
    TokRec rl[16];
    for (int k = 0; k < 16; ++k) {
        rl[k] = recs[t0 + k];
        c += 1ULL << (rl[k].e0 * 8);
        c += 1ULL << (rl[k].e1 * 8);
    }
    uint4 v;
    v.x = (unsigned)((c       ) & 0xFF) | ((unsigned)((c >>  8) & 0xFF) << 16);
    v.y = (unsigned)((c >> 16 ) & 0xFF) | ((unsigned)((c >> 24) & 0xFF) << 16);
    v.z = (unsigned)((c >> 32 ) & 0xFF) | ((unsigned)((c >> 40) & 0xFF) << 16);
    v.w = (unsigned)((c >> 48 ) & 0xFF) | ((unsigned)((c >> 56) & 0xFF) << 16);
    const uint4 own = v;
    sb[tid] = v;
    for (int d = 1; d < 256; d <<= 1) {
        __syncthreads();
        uint4 o = make_uint4(0u, 0u, 0u, 0u);
        if (tid >= d) o = sb[tid - d];
        __syncthreads();
        v.x += o.x; v.y += o.y; v.z += o.z; v.w += o.w;
        sb[tid] = v;
    }
    __syncthreads();
    const uint4 tot = sb[255];

    offlds[tid * 8 + 0] = (int)((v.x - own.x) & 0xFFFF);
    offlds[tid * 8 + 1] = (int)((v.x - own.x) >> 16);
    offlds[tid * 8 + 2] = (int)((v.y - own.y) & 0xFFFF);
    offlds[tid * 8 + 3] = (int)((v.y - own.y) >> 16);
    offlds[tid * 8 + 4] = (int)((v.z - own.z) & 0xFFFF);
    offlds[tid * 8 + 5] = (int)((v.z - own.z) >> 16);
    offlds[tid * 8 + 6] = (int)((v.w - own.w) & 0xFFFF);
    offlds[tid * 8 + 7] = (int)((v.w - own.w) >> 16);

    if (tid < 8) {
        unsigned comp = (tid < 2) ? tot.x : (tid < 4) ? tot.y : (tid < 6) ? tot.z : tot.w;
        unsigned val = (tid & 1) ? (comp >> 16) : (comp & 0xFFFF);
        loads_i[tid] = (int)val;
        loads_out[tid] = (float)val;
    }

    const int obase = tid * 8;
    for (int k = 0; k < 16; ++k) {
        const TokRec r = rl[k];
        const int tok = t0 + k;
        int d0 = offlds[obase + r.e0]++;
        smap[r.e0 * T_TOK + d0] = make_int2(tok, __float_as_int(r.g0));
        int d1 = offlds[obase + r.e1]++;
        smap[r.e1 * T_TOK + d1] = make_int2(tok, __float_as_int(r.g1));
    }
}

// ---------------- Kernel 3: scatter (R5, validated) --------------------------
__global__ __launch_bounds__(256) void scatter_kernel(const float* __restrict__ x,
                                                      const int2* __restrict__ smap,
                                                      const int* __restrict__ loads_i,
                                                      float* __restrict__ out_data,
                                                      float* __restrict__ out_tags) {
    const int tid = threadIdx.x;
    const int row0 = blockIdx.x * 4;
    const int base = tid * 8;
    const int e_first = row0 >> 12;
    const int e_last = (row0 + 3) >> 12;
    const int lf = loads_i[e_first];
    const int ll = (e_last != e_first) ? loads_i[e_last] : lf;
#pragma unroll
    for (int k = 0; k < 4; ++k) {
        const int row = row0 + k;
        const int e = row >> 12;
        const int r = row & (T_TOK - 1);
        const int le = (e == e_first) ? lf : ll;
        float* orow = out_data + (size_t)row * D_DIM;
        if (r >= le) {
            if (tid == 0) out_tags[row] = -1.0f;
            const f32x4 z = {0.f, 0.f, 0.f, 0.f};
            *reinterpret_cast<f32x4*>(orow + base) = z;
            *reinterpret_cast<f32x4*>(orow + base + 4) = z;
        } else {
            const int2 sg = smap[row];
            const int src = sg.x;
            const float g = __int_as_float(sg.y);
            if (tid == 0) out_tags[row] = (float)src;
            const float* xr = x + (size_t)src * D_DIM;
            f32x4 a = *reinterpret_cast<const f32x4*>(xr + base);
            f32x4 b = *reinterpret_cast<const f32x4*>(xr + base + 4);
            a *= g;
            b *= g;
            *reinterpret_cast<f32x4*>(orow + base) = a;
            *reinterpret_cast<f32x4*>(orow + base + 4) = b;
        }
    }
}

extern "C" void kernel_launch(void* const* d_in, const int* in_sizes, int n_in,
                              void* d_out, int out_size, void* d_ws, size_t ws_size,
                              hipStream_t stream) {
    const float* x  = (const float*)d_in[0];
    const float* Wg = (const float*)d_in[1];

    float* out       = (float*)d_out;
    float* out_data  = out;
    float* out_tags  = out + (size_t)E_EXP * T_TOK * D_DIM;
    float* out_loads = out_tags + E_EXP * T_TOK;

    char* ws = (char*)d_ws;
    TokRec* recs    = (TokRec*)ws;                         // 64 KiB
    int2*   smap    = (int2*)(ws + 65536);                 // 256 KiB
    int*    loads_i = (int*)(ws + 65536 + 262144);         // 32 B
    float*  WgT     = (float*)(ws + 65536 + 262144 + 1024);// 64 KiB

    transpose_kernel<<<D_DIM / 256, 256, 0, stream>>>(Wg, WgT);
    gating_kernel<<<T_TOK / 4, 256, 0, stream>>>(x, WgT, recs);
    scan_kernel<<<1, 256, 0, stream>>>(recs, smap, loads_i, out_loads);
    scatter_kernel<<<E_EXP * T_TOK / 4, 256, 0, stream>>>(x, smap, loads_i, out_data, out_tags);
}

// Round 12
// 77.130 us; speedup vs baseline: 1.4730x; 1.1154x over previous
//
#include <hip/hip_runtime.h>
#include <math.h>

#define T_TOK 4096
#define D_DIM 2048
#define E_EXP 8

typedef float f32x4 __attribute__((ext_vector_type(4)));

struct TokRec { int e0, e1; float g0, g1; };

// ---------------- Kernel 1: per-block Wg->LDS transpose + gating (R8 K1) ----
// 1024 blocks x 256 threads, 1 token/wave. Per-block staging of Wg into LDS
// (reads are L2/L3-hot after block 0); gating reads WgT from LDS. Validated
// in R8; cross-round algebra shows it beats transpose+L2-gating by ~3.5 us.
__global__ __launch_bounds__(256) void gating_kernel(const float* __restrict__ x,
                                                     const float* __restrict__ Wg,
                                                     TokRec* __restrict__ recs) {
    __shared__ float wgt[E_EXP * D_DIM];   // 64 KB
    const int tid = threadIdx.x;

#pragma unroll
    for (int it = 0; it < (E_EXP * D_DIM) / (256 * 4); ++it) {
        const int flat = (it * 256 + tid) * 4;
        const f32x4 w = *reinterpret_cast<const f32x4*>(Wg + flat);
        const int d = flat >> 3;
        const int e0 = flat & 7;           // 0 or 4
        wgt[(e0 + 0) * D_DIM + d] = w.x;
        wgt[(e0 + 1) * D_DIM + d] = w.y;
        wgt[(e0 + 2) * D_DIM + d] = w.z;
        wgt[(e0 + 3) * D_DIM + d] = w.w;
    }
    __syncthreads();

    const int wave = tid >> 6;
    const int lane = tid & 63;
    const int t = blockIdx.x * 4 + wave;
    const float* xr = x + (size_t)t * D_DIM;

    double acc[E_EXP];
#pragma unroll
    for (int e = 0; e < E_EXP; ++e) acc[e] = 0.0;
#pragma unroll
    for (int i = 0; i < D_DIM / 256; ++i) {
        const int d = i * 256 + lane * 4;
        const f32x4 xv = *reinterpret_cast<const f32x4*>(xr + d);
#pragma unroll
        for (int e = 0; e < E_EXP; ++e) {
            const f32x4 w = *reinterpret_cast<const f32x4*>(&wgt[e * D_DIM + d]);
            acc[e] += (double)xv.x * (double)w.x + (double)xv.y * (double)w.y
                    + (double)xv.z * (double)w.z + (double)xv.w * (double)w.w;
        }
    }
#pragma unroll
    for (int e = 0; e < E_EXP; ++e) {
        double v = acc[e];
#pragma unroll
        for (int off = 32; off > 0; off >>= 1) v += __shfl_xor(v, off, 64);
        acc[e] = v;
    }
    if (lane == 0) {
        double m = acc[0];
#pragma unroll
        for (int e = 1; e < E_EXP; ++e) m = (acc[e] > m) ? acc[e] : m;
        double Z = 0.0;
#pragma unroll
        for (int e = 0; e < E_EXP; ++e) Z += exp(acc[e] - m);
        int e0 = 0;
#pragma unroll
        for (int e = 1; e < E_EXP; ++e) if (acc[e] > acc[e0]) e0 = e;
        int e1 = (e0 == 0) ? 1 : 0;
#pragma unroll
        for (int e = 0; e < E_EXP; ++e) if (e != e0 && acc[e] > acc[e1]) e1 = e;
        TokRec r;
        r.e0 = e0; r.e1 = e1;
        r.g0 = (float)(exp(acc[e0] - m) / Z);
        r.g1 = (float)(exp(acc[e1] - m) / Z);
        recs[t] = r;
    }
}

// ---------------- Kernel 2: single-block scan (R5, validated) ----------------
__global__ __launch_bounds__(256) void scan_kernel(const TokRec* __restrict__ recs,
                                                   int2* __restrict__ smap,
                                                   int* __restrict__ loads_i,
                                                   float* __restrict__ loads_out) {
    __shared__ uint4 sb[256];
    __shared__ int offlds[256 * 8];
    const int tid = threadIdx.x;

    const int t0 = tid * 16;
    unsigned long long c = 0ULL;
    TokRec rl[16];
    for (int k = 0; k < 16; ++k) {
        rl[k] = recs[t0 + k];
        c += 1ULL << (rl[k].e0 * 8);
        c += 1ULL << (rl[k].e1 * 8);
    }
    uint4 v;
    v.x = (unsigned)((c       ) & 0xFF) | ((unsigned)((c >>  8) & 0xFF) << 16);
    v.y = (unsigned)((c >> 16 ) & 0xFF) | ((unsigned)((c >> 24) & 0xFF) << 16);
    v.z = (unsigned)((c >> 32 ) & 0xFF) | ((unsigned)((c >> 40) & 0xFF) << 16);
    v.w = (unsigned)((c >> 48 ) & 0xFF) | ((unsigned)((c >> 56) & 0xFF) << 16);
    const uint4 own = v;
    sb[tid] = v;
    for (int d = 1; d < 256; d <<= 1) {
        __syncthreads();
        uint4 o = make_uint4(0u, 0u, 0u, 0u);
        if (tid >= d) o = sb[tid - d];
        __syncthreads();
        v.x += o.x; v.y += o.y; v.z += o.z; v.w += o.w;
        sb[tid] = v;
    }
    __syncthreads();
    const uint4 tot = sb[255];

    offlds[tid * 8 + 0] = (int)((v.x - own.x) & 0xFFFF);
    offlds[tid * 8 + 1] = (int)((v.x - own.x) >> 16);
    offlds[tid * 8 + 2] = (int)((v.y - own.y) & 0xFFFF);
    offlds[tid * 8 + 3] = (int)((v.y - own.y) >> 16);
    offlds[tid * 8 + 4] = (int)((v.z - own.z) & 0xFFFF);
    offlds[tid * 8 + 5] = (int)((v.z - own.z) >> 16);
    offlds[tid * 8 + 6] = (int)((v.w - own.w) & 0xFFFF);
    offlds[tid * 8 + 7] = (int)((v.w - own.w) >> 16);

    if (tid < 8) {
        unsigned comp = (tid < 2) ? tot.x : (tid < 4) ? tot.y : (tid < 6) ? tot.z : tot.w;
        unsigned val = (tid & 1) ? (comp >> 16) : (comp & 0xFFFF);
        loads_i[tid] = (int)val;
        loads_out[tid] = (float)val;
    }

    const int obase = tid * 8;
    for (int k = 0; k < 16; ++k) {
        const TokRec r = rl[k];
        const int tok = t0 + k;
        int d0 = offlds[obase + r.e0]++;
        smap[r.e0 * T_TOK + d0] = make_int2(tok, __float_as_int(r.g0));
        int d1 = offlds[obase + r.e1]++;
        smap[r.e1 * T_TOK + d1] = make_int2(tok, __float_as_int(r.g1));
    }
}

// ---------------- Kernel 3: scatter (R5, validated) --------------------------
__global__ __launch_bounds__(256) void scatter_kernel(const float* __restrict__ x,
                                                      const int2* __restrict__ smap,
                                                      const int* __restrict__ loads_i,
                                                      float* __restrict__ out_data,
                                                      float* __restrict__ out_tags) {
    const int tid = threadIdx.x;
    const int row0 = blockIdx.x * 4;
    const int base = tid * 8;
    const int e_first = row0 >> 12;
    const int e_last = (row0 + 3) >> 12;
    const int lf = loads_i[e_first];
    const int ll = (e_last != e_first) ? loads_i[e_last] : lf;
#pragma unroll
    for (int k = 0; k < 4; ++k) {
        const int row = row0 + k;
        const int e = row >> 12;
        const int r = row & (T_TOK - 1);
        const int le = (e == e_first) ? lf : ll;
        float* orow = out_data + (size_t)row * D_DIM;
        if (r >= le) {
            if (tid == 0) out_tags[row] = -1.0f;
            const f32x4 z = {0.f, 0.f, 0.f, 0.f};
            *reinterpret_cast<f32x4*>(orow + base) = z;
            *reinterpret_cast<f32x4*>(orow + base + 4) = z;
        } else {
            const int2 sg = smap[row];
            const int src = sg.x;
            const float g = __int_as_float(sg.y);
            if (tid == 0) out_tags[row] = (float)src;
            const float* xr = x + (size_t)src * D_DIM;
            f32x4 a = *reinterpret_cast<const f32x4*>(xr + base);
            f32x4 b = *reinterpret_cast<const f32x4*>(xr + base + 4);
            a *= g;
            b *= g;
            *reinterpret_cast<f32x4*>(orow + base) = a;
            *reinterpret_cast<f32x4*>(orow + base + 4) = b;
        }
    }
}

extern "C" void kernel_launch(void* const* d_in, const int* in_sizes, int n_in,
                              void* d_out, int out_size, void* d_ws, size_t ws_size,
                              hipStream_t stream) {
    const float* x  = (const float*)d_in[0];
    const float* Wg = (const float*)d_in[1];

    float* out       = (float*)d_out;
    float* out_data  = out;
    float* out_tags  = out + (size_t)E_EXP * T_TOK * D_DIM;
    float* out_loads = out_tags + E_EXP * T_TOK;

    char* ws = (char*)d_ws;
    TokRec* recs    = (TokRec*)ws;                         // 64 KiB
    int2*   smap    = (int2*)(ws + 65536);                 // 256 KiB
    int*    loads_i = (int*)(ws + 65536 + 262144);         // 32 B

    gating_kernel<<<T_TOK / 4, 256, 0, stream>>>(x, Wg, recs);
    scan_kernel<<<1, 256, 0, stream>>>(recs, smap, loads_i, out_loads);
    scatter_kernel<<<E_EXP * T_TOK / 4, 256, 0, stream>>>(x, smap, loads_i, out_data, out_tags);
}

// Round 13
// 75.150 us; speedup vs baseline: 1.5118x; 1.0263x over previous
//
#include <hip/hip_runtime.h>
#include <math.h>

#define T_TOK 4096
#define D_DIM 2048
#define E_EXP 8

typedef float f32x4 __attribute__((ext_vector_type(4)));

struct TokRec { int e0, e1; float g0, g1; };

// ---------------- Kernel 1: per-block Wg->LDS transpose + gating ------------
// R12 winner, widened to 512-thread blocks (8 waves, 8 tokens/block,
// 512 blocks): same 16 waves/CU, but half the staging prologues.
// Per-token arithmetic identical to R5/R12 -> bit-identical routing.
__global__ __launch_bounds__(512) void gating_kernel(const float* __restrict__ x,
                                                     const float* __restrict__ Wg,
                                                     TokRec* __restrict__ recs) {
    __shared__ float wgt[E_EXP * D_DIM];   // 64 KB
    const int tid = threadIdx.x;

#pragma unroll
    for (int it = 0; it < (E_EXP * D_DIM) / (512 * 4); ++it) {   // 8 iters
        const int flat = (it * 512 + tid) * 4;
        const f32x4 w = *reinterpret_cast<const f32x4*>(Wg + flat);
        const int d = flat >> 3;
        const int e0 = flat & 7;           // 0 or 4
        wgt[(e0 + 0) * D_DIM + d] = w.x;
        wgt[(e0 + 1) * D_DIM + d] = w.y;
        wgt[(e0 + 2) * D_DIM + d] = w.z;
        wgt[(e0 + 3) * D_DIM + d] = w.w;
    }
    __syncthreads();

    const int wave = tid >> 6;             // 0..7
    const int lane = tid & 63;
    const int t = blockIdx.x * 8 + wave;
    const float* xr = x + (size_t)t * D_DIM;

    double acc[E_EXP];
#pragma unroll
    for (int e = 0; e < E_EXP; ++e) acc[e] = 0.0;
#pragma unroll
    for (int i = 0; i < D_DIM / 256; ++i) {
        const int d = i * 256 + lane * 4;
        const f32x4 xv = *reinterpret_cast<const f32x4*>(xr + d);
#pragma unroll
        for (int e = 0; e < E_EXP; ++e) {
            const f32x4 w = *reinterpret_cast<const f32x4*>(&wgt[e * D_DIM + d]);
            acc[e] += (double)xv.x * (double)w.x + (double)xv.y * (double)w.y
                    + (double)xv.z * (double)w.z + (double)xv.w * (double)w.w;
        }
    }
#pragma unroll
    for (int e = 0; e < E_EXP; ++e) {
        double v = acc[e];
#pragma unroll
        for (int off = 32; off > 0; off >>= 1) v += __shfl_xor(v, off, 64);
        acc[e] = v;
    }
    if (lane == 0) {
        double m = acc[0];
#pragma unroll
        for (int e = 1; e < E_EXP; ++e) m = (acc[e] > m) ? acc[e] : m;
        double Z = 0.0;
#pragma unroll
        for (int e = 0; e < E_EXP; ++e) Z += exp(acc[e] - m);
        int e0 = 0;
#pragma unroll
        for (int e = 1; e < E_EXP; ++e) if (acc[e] > acc[e0]) e0 = e;
        int e1 = (e0 == 0) ? 1 : 0;
#pragma unroll
        for (int e = 0; e < E_EXP; ++e) if (e != e0 && acc[e] > acc[e1]) e1 = e;
        TokRec r;
        r.e0 = e0; r.e1 = e1;
        r.g0 = (float)(exp(acc[e0] - m) / Z);
        r.g1 = (float)(exp(acc[e1] - m) / Z);
        recs[t] = r;
    }
}

// ---------------- Kernel 2: single-block scan (R5, validated) ----------------
__global__ __launch_bounds__(256) void scan_kernel(const TokRec* __restrict__ recs,
                                                   int2* __restrict__ smap,
                                                   int* __restrict__ loads_i,
                                                   float* __restrict__ loads_out) {
    __shared__ uint4 sb[256];
    __shared__ int offlds[256 * 8];
    const int tid = threadIdx.x;

    const int t0 = tid * 16;
    unsigned long long c = 0ULL;
    TokRec rl[16];
    for (int k = 0; k < 16; ++k) {
        rl[k] = recs[t0 + k];
        c += 1ULL << (rl[k].e0 * 8);
        c += 1ULL << (rl[k].e1 * 8);
    }
    uint4 v;
    v.x = (unsigned)((c       ) & 0xFF) | ((unsigned)((c >>  8) & 0xFF) << 16);
    v.y = (unsigned)((c >> 16 ) & 0xFF) | ((unsigned)((c >> 24) & 0xFF) << 16);
    v.z = (unsigned)((c >> 32 ) & 0xFF) | ((unsigned)((c >> 40) & 0xFF) << 16);
    v.w = (unsigned)((c >> 48 ) & 0xFF) | ((unsigned)((c >> 56) & 0xFF) << 16);
    const uint4 own = v;
    sb[tid] = v;
    for (int d = 1; d < 256; d <<= 1) {
        __syncthreads();
        uint4 o = make_uint4(0u, 0u, 0u, 0u);
        if (tid >= d) o = sb[tid - d];
        __syncthreads();
        v.x += o.x; v.y += o.y; v.z += o.z; v.w += o.w;
        sb[tid] = v;
    }
    __syncthreads();
    const uint4 tot = sb[255];

    offlds[tid * 8 + 0] = (int)((v.x - own.x) & 0xFFFF);
    offlds[tid * 8 + 1] = (int)((v.x - own.x) >> 16);
    offlds[tid * 8 + 2] = (int)((v.y - own.y) & 0xFFFF);
    offlds[tid * 8 + 3] = (int)((v.y - own.y) >> 16);
    offlds[tid * 8 + 4] = (int)((v.z - own.z) & 0xFFFF);
    offlds[tid * 8 + 5] = (int)((v.z - own.z) >> 16);
    offlds[tid * 8 + 6] = (int)((v.w - own.w) & 0xFFFF);
    offlds[tid * 8 + 7] = (int)((v.w - own.w) >> 16);

    if (tid < 8) {
        unsigned comp = (tid < 2) ? tot.x : (tid < 4) ? tot.y : (tid < 6) ? tot.z : tot.w;
        unsigned val = (tid & 1) ? (comp >> 16) : (comp & 0xFFFF);
        loads_i[tid] = (int)val;
        loads_out[tid] = (float)val;
    }

    const int obase = tid * 8;
    for (int k = 0; k < 16; ++k) {
        const TokRec r = rl[k];
        const int tok = t0 + k;
        int d0 = offlds[obase + r.e0]++;
        smap[r.e0 * T_TOK + d0] = make_int2(tok, __float_as_int(r.g0));
        int d1 = offlds[obase + r.e1]++;
        smap[r.e1 * T_TOK + d1] = make_int2(tok, __float_as_int(r.g1));
    }
}

// ---------------- Kernel 3: scatter (R5, validated) --------------------------
__global__ __launch_bounds__(256) void scatter_kernel(const float* __restrict__ x,
                                                      const int2* __restrict__ smap,
                                                      const int* __restrict__ loads_i,
                                                      float* __restrict__ out_data,
                                                      float* __restrict__ out_tags) {
    const int tid = threadIdx.x;
    const int row0 = blockIdx.x * 4;
    const int base = tid * 8;
    const int e_first = row0 >> 12;
    const int e_last = (row0 + 3) >> 12;
    const int lf = loads_i[e_first];
    const int ll = (e_last != e_first) ? loads_i[e_last] : lf;
#pragma unroll
    for (int k = 0; k < 4; ++k) {
        const int row = row0 + k;
        const int e = row >> 12;
        const int r = row & (T_TOK - 1);
        const int le = (e == e_first) ? lf : ll;
        float* orow = out_data + (size_t)row * D_DIM;
        if (r >= le) {
            if (tid == 0) out_tags[row] = -1.0f;
            const f32x4 z = {0.f, 0.f, 0.f, 0.f};
            *reinterpret_cast<f32x4*>(orow + base) = z;
            *reinterpret_cast<f32x4*>(orow + base + 4) = z;
        } else {
            const int2 sg = smap[row];
            const int src = sg.x;
            const float g = __int_as_float(sg.y);
            if (tid == 0) out_tags[row] = (float)src;
            const float* xr = x + (size_t)src * D_DIM;
            f32x4 a = *reinterpret_cast<const f32x4*>(xr + base);
            f32x4 b = *reinterpret_cast<const f32x4*>(xr + base + 4);
            a *= g;
            b *= g;
            *reinterpret_cast<f32x4*>(orow + base) = a;
            *reinterpret_cast<f32x4*>(orow + base + 4) = b;
        }
    }
}

extern "C" void kernel_launch(void* const* d_in, const int* in_sizes, int n_in,
                              void* d_out, int out_size, void* d_ws, size_t ws_size,
                              hipStream_t stream) {
    const float* x  = (const float*)d_in[0];
    const float* Wg = (const float*)d_in[1];

    float* out       = (float*)d_out;
    float* out_data  = out;
    float* out_tags  = out + (size_t)E_EXP * T_TOK * D_DIM;
    float* out_loads = out_tags + E_EXP * T_TOK;

    char* ws = (char*)d_ws;
    TokRec* recs    = (TokRec*)ws;                         // 64 KiB
    int2*   smap    = (int2*)(ws + 65536);                 // 256 KiB
    int*    loads_i = (int*)(ws + 65536 + 262144);         // 32 B

    gating_kernel<<<T_TOK / 8, 512, 0, stream>>>(x, Wg, recs);
    scan_kernel<<<1, 256, 0, stream>>>(recs, smap, loads_i, out_loads);
    scatter_kernel<<<E_EXP * T_TOK / 4, 256, 0, stream>>>(x, smap, loads_i, out_data, out_tags);
}

// Round 14
// 73.799 us; speedup vs baseline: 1.5395x; 1.0183x over previous
//
#include <hip/hip_runtime.h>
#include <math.h>

#define T_TOK 4096
#define D_DIM 2048
#define E_EXP 8

typedef float f32x4 __attribute__((ext_vector_type(4)));

struct TokRec { int e0, e1; float g0, g1; };

// ---------------- Kernel 1: per-block Wg->LDS transpose + gating ------------
// 1024-thread blocks (16 waves, 16 tokens/block, 256 blocks = exactly 1/CU):
// same 16 waves/CU as R12/R13, one staging prologue per CU total.
// Per-token arithmetic identical to R5/R12/R13 -> bit-identical routing.
__global__ __launch_bounds__(1024) void gating_kernel(const float* __restrict__ x,
                                                      const float* __restrict__ Wg,
                                                      TokRec* __restrict__ recs) {
    __shared__ float wgt[E_EXP * D_DIM];   // 64 KB
    const int tid = threadIdx.x;

#pragma unroll
    for (int it = 0; it < (E_EXP * D_DIM) / (1024 * 4); ++it) {   // 4 iters
        const int flat = (it * 1024 + tid) * 4;
        const f32x4 w = *reinterpret_cast<const f32x4*>(Wg + flat);
        const int d = flat >> 3;
        const int e0 = flat & 7;           // 0 or 4
        wgt[(e0 + 0) * D_DIM + d] = w.x;
        wgt[(e0 + 1) * D_DIM + d] = w.y;
        wgt[(e0 + 2) * D_DIM + d] = w.z;
        wgt[(e0 + 3) * D_DIM + d] = w.w;
    }
    __syncthreads();

    const int wave = tid >> 6;             // 0..15
    const int lane = tid & 63;
    const int t = blockIdx.x * 16 + wave;
    const float* xr = x + (size_t)t * D_DIM;

    double acc[E_EXP];
#pragma unroll
    for (int e = 0; e < E_EXP; ++e) acc[e] = 0.0;
#pragma unroll
    for (int i = 0; i < D_DIM / 256; ++i) {
        const int d = i * 256 + lane * 4;
        const f32x4 xv = *reinterpret_cast<const f32x4*>(xr + d);
#pragma unroll
        for (int e = 0; e < E_EXP; ++e) {
            const f32x4 w = *reinterpret_cast<const f32x4*>(&wgt[e * D_DIM + d]);
            acc[e] += (double)xv.x * (double)w.x + (double)xv.y * (double)w.y
                    + (double)xv.z * (double)w.z + (double)xv.w * (double)w.w;
        }
    }
#pragma unroll
    for (int e = 0; e < E_EXP; ++e) {
        double v = acc[e];
#pragma unroll
        for (int off = 32; off > 0; off >>= 1) v += __shfl_xor(v, off, 64);
        acc[e] = v;
    }
    if (lane == 0) {
        double m = acc[0];
#pragma unroll
        for (int e = 1; e < E_EXP; ++e) m = (acc[e] > m) ? acc[e] : m;
        double Z = 0.0;
#pragma unroll
        for (int e = 0; e < E_EXP; ++e) Z += exp(acc[e] - m);
        int e0 = 0;
#pragma unroll
        for (int e = 1; e < E_EXP; ++e) if (acc[e] > acc[e0]) e0 = e;
        int e1 = (e0 == 0) ? 1 : 0;
#pragma unroll
        for (int e = 0; e < E_EXP; ++e) if (e != e0 && acc[e] > acc[e1]) e1 = e;
        TokRec r;
        r.e0 = e0; r.e1 = e1;
        r.g0 = (float)(exp(acc[e0] - m) / Z);
        r.g1 = (float)(exp(acc[e1] - m) / Z);
        recs[t] = r;
    }
}

// ---------------- Kernel 2: single-block scan, 1024 threads ------------------
// 4 tokens/thread (was 16): the serial per-thread load+LDS-RMW loop is the
// scan's cost; Hillis-Steele depth only grows 8->10. Same deterministic
// token order -> identical smap/loads to the 256-thread version.
__global__ __launch_bounds__(1024) void scan_kernel(const TokRec* __restrict__ recs,
                                                    int2* __restrict__ smap,
                                                    int* __restrict__ loads_i,
                                                    float* __restrict__ loads_out) {
    __shared__ uint4 sb[1024];         // 16 KB
    __shared__ int offlds[1024 * 8];   // 32 KB
    const int tid = threadIdx.x;

    const int t0 = tid * 4;
    unsigned long long c = 0ULL;
    TokRec rl[4];
#pragma unroll
    for (int k = 0; k < 4; ++k) {
        rl[k] = recs[t0 + k];
        c += 1ULL << (rl[k].e0 * 8);
        c += 1ULL << (rl[k].e1 * 8);
    }
    uint4 v;
    v.x = (unsigned)((c       ) & 0xFF) | ((unsigned)((c >>  8) & 0xFF) << 16);
    v.y = (unsigned)((c >> 16 ) & 0xFF) | ((unsigned)((c >> 24) & 0xFF) << 16);
    v.z = (unsigned)((c >> 32 ) & 0xFF) | ((unsigned)((c >> 40) & 0xFF) << 16);
    v.w = (unsigned)((c >> 48 ) & 0xFF) | ((unsigned)((c >> 56) & 0xFF) << 16);
    const uint4 own = v;
    sb[tid] = v;
    for (int d = 1; d < 1024; d <<= 1) {
        __syncthreads();
        uint4 o = make_uint4(0u, 0u, 0u, 0u);
        if (tid >= d) o = sb[tid - d];
        __syncthreads();
        v.x += o.x; v.y += o.y; v.z += o.z; v.w += o.w;
        sb[tid] = v;
    }
    __syncthreads();
    const uint4 tot = sb[1023];

    offlds[tid * 8 + 0] = (int)((v.x - own.x) & 0xFFFF);
    offlds[tid * 8 + 1] = (int)((v.x - own.x) >> 16);
    offlds[tid * 8 + 2] = (int)((v.y - own.y) & 0xFFFF);
    offlds[tid * 8 + 3] = (int)((v.y - own.y) >> 16);
    offlds[tid * 8 + 4] = (int)((v.z - own.z) & 0xFFFF);
    offlds[tid * 8 + 5] = (int)((v.z - own.z) >> 16);
    offlds[tid * 8 + 6] = (int)((v.w - own.w) & 0xFFFF);
    offlds[tid * 8 + 7] = (int)((v.w - own.w) >> 16);

    if (tid < 8) {
        unsigned comp = (tid < 2) ? tot.x : (tid < 4) ? tot.y : (tid < 6) ? tot.z : tot.w;
        unsigned val = (tid & 1) ? (comp >> 16) : (comp & 0xFFFF);
        loads_i[tid] = (int)val;
        loads_out[tid] = (float)val;
    }

    const int obase = tid * 8;
#pragma unroll
    for (int k = 0; k < 4; ++k) {
        const TokRec r = rl[k];
        const int tok = t0 + k;
        int d0 = offlds[obase + r.e0]++;
        smap[r.e0 * T_TOK + d0] = make_int2(tok, __float_as_int(r.g0));
        int d1 = offlds[obase + r.e1]++;
        smap[r.e1 * T_TOK + d1] = make_int2(tok, __float_as_int(r.g1));
    }
}

// ---------------- Kernel 3: scatter (R5, validated — at write roofline) ------
__global__ __launch_bounds__(256) void scatter_kernel(const float* __restrict__ x,
                                                      const int2* __restrict__ smap,
                                                      const int* __restrict__ loads_i,
                                                      float* __restrict__ out_data,
                                                      float* __restrict__ out_tags) {
    const int tid = threadIdx.x;
    const int row0 = blockIdx.x * 4;
    const int base = tid * 8;
    const int e_first = row0 >> 12;
    const int e_last = (row0 + 3) >> 12;
    const int lf = loads_i[e_first];
    const int ll = (e_last != e_first) ? loads_i[e_last] : lf;
#pragma unroll
    for (int k = 0; k < 4; ++k) {
        const int row = row0 + k;
        const int e = row >> 12;
        const int r = row & (T_TOK - 1);
        const int le = (e == e_first) ? lf : ll;
        float* orow = out_data + (size_t)row * D_DIM;
        if (r >= le) {
            if (tid == 0) out_tags[row] = -1.0f;
            const f32x4 z = {0.f, 0.f, 0.f, 0.f};
            *reinterpret_cast<f32x4*>(orow + base) = z;
            *reinterpret_cast<f32x4*>(orow + base + 4) = z;
        } else {
            const int2 sg = smap[row];
            const int src = sg.x;
            const float g = __int_as_float(sg.y);
            if (tid == 0) out_tags[row] = (float)src;
            const float* xr = x + (size_t)src * D_DIM;
            f32x4 a = *reinterpret_cast<const f32x4*>(xr + base);
            f32x4 b = *reinterpret_cast<const f32x4*>(xr + base + 4);
            a *= g;
            b *= g;
            *reinterpret_cast<f32x4*>(orow + base) = a;
            *reinterpret_cast<f32x4*>(orow + base + 4) = b;
        }
    }
}

extern "C" void kernel_launch(void* const* d_in, const int* in_sizes, int n_in,
                              void* d_out, int out_size, void* d_ws, size_t ws_size,
                              hipStream_t stream) {
    const float* x  = (const float*)d_in[0];
    const float* Wg = (const float*)d_in[1];

    float* out       = (float*)d_out;
    float* out_data  = out;
    float* out_tags  = out + (size_t)E_EXP * T_TOK * D_DIM;
    float* out_loads = out_tags + E_EXP * T_TOK;

    char* ws = (char*)d_ws;
    TokRec* recs    = (TokRec*)ws;                         // 64 KiB
    int2*   smap    = (int2*)(ws + 65536);                 // 256 KiB
    int*    loads_i = (int*)(ws + 65536 + 262144);         // 32 B

    gating_kernel<<<T_TOK / 16, 1024, 0, stream>>>(x, Wg, recs);
    scan_kernel<<<1, 1024, 0, stream>>>(recs, smap, loads_i, out_loads);
    scatter_kernel<<<E_EXP * T_TOK / 4, 256, 0, stream>>>(x, smap, loads_i, out_data, out_tags);
}